// Round 14
// baseline (160.620 us; speedup 1.0000x reference)
//
#include <hip/hip_runtime.h>
#include <hip/hip_fp8.h>
#include <stdint.h>
#include <math.h>

#define C_NUM 2048
#define N_TOT 4096
#define B_TOT 4096
#define KNOWN 1024

typedef __attribute__((ext_vector_type(4))) float f32x4;
typedef __attribute__((ext_vector_type(4))) int i32x4;
typedef __attribute__((ext_vector_type(8))) int i32x8;

// ---- Kernel 1: transpose + fp8 convert + colsum/norm2 (float4 loads) -----
__global__ __launch_bounds__(256) void transpose_stats_kernel(
    const float* __restrict__ prob,
    const float* __restrict__ prob_s,
    float* __restrict__ colsum,
    float* __restrict__ norm2,
    uint8_t* __restrict__ Pn) {
  __shared__ float tile[64][68];
  const int tid = threadIdx.x;
  const int c0 = blockIdx.x * 64;      // class tile (0..4095)
  const int b0 = blockIdx.y * 64;      // batch tile
  const float* src = (c0 < C_NUM) ? prob : prob_s;
  const int colbase = (c0 & (C_NUM - 1));

  {
    const int row = tid >> 4;          // 0..15 (+16c)
    const int f4c = tid & 15;
#pragma unroll
    for (int c = 0; c < 4; ++c) {
      const float4 v = *(const float4*)(src + (size_t)(b0 + row + 16 * c) * C_NUM +
                                        colbase + f4c * 4);
      *(float4*)&tile[row + 16 * c][f4c * 4] = v;
    }
  }
  __syncthreads();

  {
    const int ci = tid >> 2;           // class within tile 0..63
    const int qb = tid & 3;            // batch quarter
    float s = 0.f, s2 = 0.f;
    uint8_t bytes[16];
#pragma unroll
    for (int k = 0; k < 16; ++k) {
      float v = tile[qb * 16 + k][ci];
      s += v;
      s2 += v * v;
      __hip_fp8_e4m3 q(v);
      bytes[k] = q.__x;
    }
    *(i32x4*)(Pn + (size_t)(c0 + ci) * B_TOT + b0 + qb * 16) = *(i32x4*)bytes;
    s += __shfl_xor(s, 1);
    s += __shfl_xor(s, 2);
    s2 += __shfl_xor(s2, 1);
    s2 += __shfl_xor(s2, 2);
    if (qb == 0) {
      atomicAdd(&colsum[c0 + ci], s);
      atomicAdd(&norm2[c0 + ci], s2);
    }
  }
}

// ---- Kernel 2: symmetric MX-fp8 GEMM (16x16x128) + softmax epilogue ------
// R13 geometry/layout (measured 0-conflict): 128x128 tile, 256 threads =
// 4 waves (2x2), wave tile 64x64 (acc[4][4] f32x4). K-step 256B, A+B in one
// 64KB buffer, 256B rows, 16B granule g of row r at phys slot g^(r&15).
// NEW (T14): next K-tile staged global->REGISTERS during compute, written
// regs->LDS after the read-drain barrier. Latency hides under compute; no
// dbuf footprint. Diag jobs skip B staging (read B frags from A region).
__global__ __launch_bounds__(256, 2) void simgemm_kernel(
    const uint8_t* __restrict__ Pn,
    const float* __restrict__ norm2,
    float* __restrict__ sumexp,
    float* __restrict__ pos) {
  __shared__ __align__(16) char lds[65536];  // A at 0, B at 32768

  const int tid = threadIdx.x;
  const int l = tid & 63;
  const int w = tid >> 6;            // wave 0..3
  const int wr = w >> 1, wc = w & 1; // 2x2 wave grid

  // bijective XCD-chunked job swizzle: 528 = 8 * 66
  const int job = (blockIdx.x & 7) * 66 + (blockIdx.x >> 3);
  int t = job;
  int it = 0, rem = 32;
  while (t >= rem) { t -= rem; ++it; --rem; }
  const int jt = it + t;
  const int ib = it * 128;
  const int jb = jt * 128;
  const bool diag = (it == jt);

  // staging addresses (R13-verified): thread tid covers granules
  // G = tid + 256c (c=0..7): row = (tid>>4)+16c, phys slot = tid&15,
  // logical slot = (tid&15) ^ ((tid>>4)&15) (constant across c).
  const int glog = (tid & 15) ^ ((tid >> 4) & 15);
  const char* gA = (const char*)Pn + (size_t)(ib + (tid >> 4)) * B_TOT + glog * 16;
  const char* gB = (const char*)Pn + (size_t)(jb + (tid >> 4)) * B_TOT + glog * 16;
  const int ldsOf = tid * 16;

  f32x4 acc[4][4];
#pragma unroll
  for (int a = 0; a < 4; ++a)
#pragma unroll
    for (int b = 0; b < 4; ++b)
      acc[a][b] = (f32x4){0.f, 0.f, 0.f, 0.f};

  // fragment geometry (R13-verified)
  const int lx = l & 15;
  const int ra = wr * 64 + lx;
  const int rb = wc * 64 + lx;
  const int bofs = diag ? 0 : 32768;   // diag: B frags come from A region

  // ---- reg-staging helpers ----
  i32x4 rA[8], rB[8];
#define LOADREGS(koff)                                                     \
  do {                                                                     \
    _Pragma("unroll")                                                      \
    for (int c = 0; c < 8; ++c)                                            \
      rA[c] = *(const i32x4*)(gA + (size_t)(16 * c) * B_TOT + (koff));     \
    if (!diag) {                                                           \
      _Pragma("unroll")                                                    \
      for (int c = 0; c < 8; ++c)                                          \
        rB[c] = *(const i32x4*)(gB + (size_t)(16 * c) * B_TOT + (koff));   \
    }                                                                      \
  } while (0)

#define WRITELDS()                                                         \
  do {                                                                     \
    _Pragma("unroll")                                                      \
    for (int c = 0; c < 8; ++c)                                            \
      *(i32x4*)(lds + c * 4096 + ldsOf) = rA[c];                           \
    if (!diag) {                                                           \
      _Pragma("unroll")                                                    \
      for (int c = 0; c < 8; ++c)                                          \
        *(i32x4*)(lds + 32768 + c * 4096 + ldsOf) = rB[c];                 \
    }                                                                      \
  } while (0)

  // prologue: stage tile 0
  LOADREGS(0);
  WRITELDS();
  __syncthreads();

  const int NT = B_TOT / 256;   // 16 K-steps of 256 bytes
  for (int kt = 0; kt < NT; ++kt) {
    // issue next tile's loads (async; land during compute)
    if (kt + 1 < NT) LOADREGS((kt + 1) * 256);

    // compute step kt
#pragma unroll
    for (int q = 0; q < 2; ++q) {
      const int ph0 = ((q * 8 + (l >> 4) * 2) ^ lx) * 16;
      i32x8 af[4];
#pragma unroll
      for (int fm = 0; fm < 4; ++fm) {
        const char* p = lds + (ra + fm * 16) * 256;
        i32x4 lo = *(const i32x4*)(p + ph0);
        i32x4 hi = *(const i32x4*)(p + (ph0 ^ 16));
        af[fm] = __builtin_shufflevector(lo, hi, 0, 1, 2, 3, 4, 5, 6, 7);
      }
      __builtin_amdgcn_s_setprio(1);
#pragma unroll
      for (int fn = 0; fn < 4; ++fn) {
        const char* p = lds + bofs + (rb + fn * 16) * 256;
        i32x4 lo = *(const i32x4*)(p + ph0);
        i32x4 hi = *(const i32x4*)(p + (ph0 ^ 16));
        i32x8 bf = __builtin_shufflevector(lo, hi, 0, 1, 2, 3, 4, 5, 6, 7);
#pragma unroll
        for (int fm = 0; fm < 4; ++fm)
          acc[fm][fn] = __builtin_amdgcn_mfma_scale_f32_16x16x128_f8f6f4(
              af[fm], bf, acc[fm][fn], 0, 0, 0, 0x7F7F7F7F, 0, 0x7F7F7F7F);
      }
      __builtin_amdgcn_s_setprio(0);
    }

    if (kt + 1 < NT) {
      __syncthreads();   // all reads of kt done (drains vmcnt: regs landed)
      WRITELDS();        // overwrite in place with tile kt+1
      __syncthreads();   // writes visible
    }
  }
#undef LOADREGS
#undef WRITELDS

  // ---- epilogue (R13-verified): v = 2 * dot * inv_i * inv_j ----
  float invj[4];
#pragma unroll
  for (int fn = 0; fn < 4; ++fn)
    invj[fn] = 1.0f / fmaxf(sqrtf(norm2[jb + wc * 64 + fn * 16 + lx]), 1e-8f);

  if (diag) {
#pragma unroll
    for (int fm = 0; fm < 4; ++fm) {
#pragma unroll
      for (int r = 0; r < 4; ++r) {
        const int i = ib + wr * 64 + fm * 16 + (l >> 4) * 4 + r;
        const float invi = 1.0f / fmaxf(sqrtf(norm2[i]), 1e-8f);
        float rs = 0.f;
#pragma unroll
        for (int fn = 0; fn < 4; ++fn) {
          const int j = jb + wc * 64 + fn * 16 + lx;
          float v = acc[fm][fn][r] * 2.0f * invi * invj[fn];
          if (j != i)   // i^2048 can't occur inside a diagonal block
            rs += (((i & 1024) == 0) && (j < KNOWN)) ? 1.0f : __expf(v);
        }
        rs += __shfl_xor(rs, 1);
        rs += __shfl_xor(rs, 2);
        rs += __shfl_xor(rs, 4);
        rs += __shfl_xor(rs, 8);
        if (lx == 0) atomicAdd(&sumexp[i], rs);
      }
    }
  } else {
    float cs[4] = {0.f, 0.f, 0.f, 0.f};
#pragma unroll
    for (int fm = 0; fm < 4; ++fm) {
#pragma unroll
      for (int r = 0; r < 4; ++r) {
        const int i = ib + wr * 64 + fm * 16 + (l >> 4) * 4 + r;
        const float invi = 1.0f / fmaxf(sqrtf(norm2[i]), 1e-8f);
        float rs = 0.f;
#pragma unroll
        for (int fn = 0; fn < 4; ++fn) {
          const int j = jb + wc * 64 + fn * 16 + lx;
          float v = acc[fm][fn][r] * 2.0f * invi * invj[fn];
          if (j == (i ^ 2048)) {
            pos[i] = v;          // symmetric entry, same value
            pos[j] = v;
          } else {               // j != i always holds off-diagonal
            float e = __expf(v);
            rs += (((i & 1024) == 0) && (j < KNOWN)) ? 1.0f : e;
            cs[fn] += (((j & 1024) == 0) && (i < KNOWN)) ? 1.0f : e;
          }
        }
        rs += __shfl_xor(rs, 1);
        rs += __shfl_xor(rs, 2);
        rs += __shfl_xor(rs, 4);
        rs += __shfl_xor(rs, 8);
        if (lx == 0) atomicAdd(&sumexp[i], rs);
      }
    }
#pragma unroll
    for (int fn = 0; fn < 4; ++fn) {
      cs[fn] += __shfl_xor(cs[fn], 16);
      cs[fn] += __shfl_xor(cs[fn], 32);
    }
    if (l < 16) {
#pragma unroll
      for (int fn = 0; fn < 4; ++fn)
        atomicAdd(&sumexp[jb + wc * 64 + fn * 16 + l], cs[fn]);
    }
  }
}

// ---- Kernel 3: finalize ---------------------------------------------------
__device__ float block_reduce_256(float v, volatile float* red) {
#pragma unroll
  for (int m = 32; m >= 1; m >>= 1) v += __shfl_xor(v, m);
  __syncthreads();
  if ((threadIdx.x & 63) == 0) red[threadIdx.x >> 6] = v;
  __syncthreads();
  return red[0] + red[1] + red[2] + red[3];
}

__global__ void finalize_kernel(const float* __restrict__ colsum,
                                const float* __restrict__ sumexp,
                                const float* __restrict__ pos,
                                float* __restrict__ out) {
  __shared__ float red[4];
  int t = threadIdx.x;
  float ce = 0.f, t1 = 0.f, t2 = 0.f;
  for (int i = t; i < N_TOT; i += 256) ce += logf(sumexp[i]) - pos[i];
  for (int c = t; c < C_NUM; c += 256) t1 += colsum[c];
  for (int c = t; c < C_NUM; c += 256) t2 += colsum[C_NUM + c];
  ce = block_reduce_256(ce, red);
  t1 = block_reduce_256(t1, red);
  t2 = block_reduce_256(t2, red);
  float e1 = 0.f, e2 = 0.f;
  for (int c = t; c < C_NUM; c += 256) {
    float m = colsum[c] / t1;
    e1 += m * logf(m);
  }
  for (int c = t; c < C_NUM; c += 256) {
    float m = colsum[C_NUM + c] / t2;
    e2 += m * logf(m);
  }
  e1 = block_reduce_256(e1, red);
  e2 = block_reduce_256(e2, red);
  if (t == 0) {
    float reg = logf((float)C_NUM) + e1 + logf((float)C_NUM) + e2;
    out[0] = ce / (float)N_TOT + reg;
  }
}

extern "C" void kernel_launch(void* const* d_in, const int* in_sizes, int n_in,
                              void* d_out, int out_size, void* d_ws, size_t ws_size,
                              hipStream_t stream) {
  const float* prob = (const float*)d_in[0];
  const float* prob_s = (const float*)d_in[1];
  float* out = (float*)d_out;

  char* ws = (char*)d_ws;
  uint8_t* Pn = (uint8_t*)ws;                                   // 16 MB fp8
  float* norm2 = (float*)(ws + (size_t)N_TOT * B_TOT);          // 4096 f32
  float* colsum = norm2 + N_TOT;                                // 4096 f32
  float* sumexp = colsum + N_TOT;                               // 4096 f32
  float* pos = sumexp + N_TOT;                                  // 4096 f32

  // zero the atomic accumulators (norm2, colsum, sumexp contiguous)
  hipMemsetAsync(norm2, 0, (size_t)3 * N_TOT * sizeof(float), stream);

  transpose_stats_kernel<<<dim3(64, 64), 256, 0, stream>>>(
      prob, prob_s, colsum, norm2, Pn);
  simgemm_kernel<<<528, 256, 0, stream>>>(Pn, norm2, sumexp, pos);
  finalize_kernel<<<1, 256, 0, stream>>>(colsum, sumexp, pos, out);
}

// Round 15
// 101.539 us; speedup vs baseline: 1.5819x; 1.5819x over previous
//
#include <hip/hip_runtime.h>
#include <hip/hip_fp8.h>
#include <stdint.h>
#include <math.h>

#define C_NUM 2048
#define N_TOT 4096
#define B_TOT 4096
#define KNOWN 1024

typedef __attribute__((ext_vector_type(4))) float f32x4;
typedef __attribute__((ext_vector_type(4))) int i32x4;
typedef __attribute__((ext_vector_type(8))) int i32x8;

__device__ __forceinline__ void gld16(const void* g, void* l) {
  __builtin_amdgcn_global_load_lds(
      (const __attribute__((address_space(1))) void*)g,
      (__attribute__((address_space(3))) void*)l, 16, 0, 0);
}

// ---- Kernel 1: transpose + fp8 convert + colsum/norm2 (float4 loads) -----
__global__ __launch_bounds__(256) void transpose_stats_kernel(
    const float* __restrict__ prob,
    const float* __restrict__ prob_s,
    float* __restrict__ colsum,
    float* __restrict__ norm2,
    uint8_t* __restrict__ Pn) {
  __shared__ float tile[64][68];
  const int tid = threadIdx.x;
  const int c0 = blockIdx.x * 64;      // class tile (0..4095)
  const int b0 = blockIdx.y * 64;      // batch tile
  const float* src = (c0 < C_NUM) ? prob : prob_s;
  const int colbase = (c0 & (C_NUM - 1));

  {
    const int row = tid >> 4;          // 0..15 (+16c)
    const int f4c = tid & 15;
#pragma unroll
    for (int c = 0; c < 4; ++c) {
      const float4 v = *(const float4*)(src + (size_t)(b0 + row + 16 * c) * C_NUM +
                                        colbase + f4c * 4);
      *(float4*)&tile[row + 16 * c][f4c * 4] = v;
    }
  }
  __syncthreads();

  {
    const int ci = tid >> 2;           // class within tile 0..63
    const int qb = tid & 3;            // batch quarter
    float s = 0.f, s2 = 0.f;
    uint8_t bytes[16];
#pragma unroll
    for (int k = 0; k < 16; ++k) {
      float v = tile[qb * 16 + k][ci];
      s += v;
      s2 += v * v;
      __hip_fp8_e4m3 q(v);
      bytes[k] = q.__x;
    }
    *(i32x4*)(Pn + (size_t)(c0 + ci) * B_TOT + b0 + qb * 16) = *(i32x4*)bytes;
    s += __shfl_xor(s, 1);
    s += __shfl_xor(s, 2);
    s2 += __shfl_xor(s2, 1);
    s2 += __shfl_xor(s2, 2);
    if (qb == 0) {
      atomicAdd(&colsum[c0 + ci], s);
      atomicAdd(&norm2[c0 + ci], s2);
    }
  }
}

// ---- Kernel 2: symmetric MX-fp8 GEMM (16x16x128) + softmax epilogue ------
// Triangular tile pairs (jt >= it), 128x128 tile, 256 threads = 4 waves
// (2x2), wave tile 64x64 (acc[4][4] f32x4, 1KB LDS/MFMA — R13-verified).
// K-step = 128B -> A+B tiles 2x16KB per buffer, DOUBLE-buffered in 64KB.
// Staging via global_load_lds (zero VGPR cost — R14 lesson), 8 gld16/thread
// per step, 8-slot row-XOR swizzle (phys16B = logical ^ (row&7), pre-
// permuted global source, linear LDS dest; 2-way aliasing = free, m136).
// R8-proven 2-phase loop: STAGE(next) -> frags+MFMA -> one syncthreads.
__global__ __launch_bounds__(256) void simgemm_kernel(
    const uint8_t* __restrict__ Pn,
    const float* __restrict__ norm2,
    float* __restrict__ sumexp,
    float* __restrict__ pos) {
  __shared__ __align__(16) char lds[65536];  // buf q at q*32768: A +0, B +16384

  const int tid = threadIdx.x;
  const int l = tid & 63;
  const int w = tid >> 6;            // wave 0..3
  const int wr = w >> 1, wc = w & 1; // 2x2 wave grid

  // bijective XCD-chunked job swizzle: 528 = 8 * 66
  const int job = (blockIdx.x & 7) * 66 + (blockIdx.x >> 3);
  int t = job;
  int it = 0, rem = 32;
  while (t >= rem) { t -= rem; ++it; --rem; }
  const int jt = it + t;
  const int ib = it * 128;
  const int jb = jt * 128;
  const bool diag = (it == jt);

  // staging: thread tid covers granules G = tid + 256c (c=0..3) of each
  // 128x128B operand tile. row = G>>3 = (tid>>3)+32c, phys slot = tid&7,
  // logical slot = (tid&7) ^ ((tid>>3)&7)  (32c == 0 mod 8).
  const int glog = (tid & 7) ^ ((tid >> 3) & 7);
  const char* gA = (const char*)Pn + (size_t)(ib + (tid >> 3)) * B_TOT + glog * 16;
  const char* gB = (const char*)Pn + (size_t)(jb + (tid >> 3)) * B_TOT + glog * 16;
  const int ldsOf = tid * 16;

  f32x4 acc[4][4];
#pragma unroll
  for (int a = 0; a < 4; ++a)
#pragma unroll
    for (int b = 0; b < 4; ++b)
      acc[a][b] = (f32x4){0.f, 0.f, 0.f, 0.f};

  // fragment geometry: rows of 128B; lane k-granules lg = (l>>4)*2, lg+1;
  // phys = lg ^ (row&7) = lg ^ (l&7); partner = ^1 -> byte ph0 and ph0^16.
  const int lx = l & 15;
  const int ra = wr * 64 + lx;
  const int rb = wc * 64 + lx;
  const int ph0 = ((((l >> 4) * 2) ^ (l & 7))) * 16;
  const int bofs = diag ? 0 : 16384;   // diag: B frags from A region

#define STAGE(buf, koff)                                                    \
  do {                                                                      \
    _Pragma("unroll")                                                       \
    for (int c = 0; c < 4; ++c)                                             \
      gld16(gA + (size_t)(32 * c) * B_TOT + (koff),                         \
            lds + (buf) * 32768 + c * 4096 + ldsOf);                        \
    if (!diag) {                                                            \
      _Pragma("unroll")                                                     \
      for (int c = 0; c < 4; ++c)                                           \
        gld16(gB + (size_t)(32 * c) * B_TOT + (koff),                       \
              lds + (buf) * 32768 + 16384 + c * 4096 + ldsOf);              \
    }                                                                       \
  } while (0)

  STAGE(0, 0);
  __syncthreads();

  int cur = 0;
  const int NT = B_TOT / 128;   // 32 K-steps of 128 bytes
  for (int kt = 0; kt < NT; ++kt) {
    if (kt + 1 < NT) STAGE(cur ^ 1, (kt + 1) * 128);

    const char* Abase = lds + cur * 32768;
    const char* Bbase = Abase + bofs;

    i32x8 af[4];
#pragma unroll
    for (int fm = 0; fm < 4; ++fm) {
      const char* p = Abase + (ra + fm * 16) * 128;
      i32x4 lo = *(const i32x4*)(p + ph0);
      i32x4 hi = *(const i32x4*)(p + (ph0 ^ 16));
      af[fm] = __builtin_shufflevector(lo, hi, 0, 1, 2, 3, 4, 5, 6, 7);
    }
    __builtin_amdgcn_s_setprio(1);
#pragma unroll
    for (int fn = 0; fn < 4; ++fn) {
      const char* p = Bbase + (rb + fn * 16) * 128;
      i32x4 lo = *(const i32x4*)(p + ph0);
      i32x4 hi = *(const i32x4*)(p + (ph0 ^ 16));
      i32x8 bf = __builtin_shufflevector(lo, hi, 0, 1, 2, 3, 4, 5, 6, 7);
#pragma unroll
      for (int fm = 0; fm < 4; ++fm)
        acc[fm][fn] = __builtin_amdgcn_mfma_scale_f32_16x16x128_f8f6f4(
            af[fm], bf, acc[fm][fn], 0, 0, 0, 0x7F7F7F7F, 0, 0x7F7F7F7F);
    }
    __builtin_amdgcn_s_setprio(0);
    __syncthreads();   // staging of next landed + reads of cur done
    cur ^= 1;
  }
#undef STAGE

  // ---- epilogue (R13-verified): v = 2 * dot * inv_i * inv_j ----
  float invj[4];
#pragma unroll
  for (int fn = 0; fn < 4; ++fn)
    invj[fn] = 1.0f / fmaxf(sqrtf(norm2[jb + wc * 64 + fn * 16 + lx]), 1e-8f);

  if (diag) {
#pragma unroll
    for (int fm = 0; fm < 4; ++fm) {
#pragma unroll
      for (int r = 0; r < 4; ++r) {
        const int i = ib + wr * 64 + fm * 16 + (l >> 4) * 4 + r;
        const float invi = 1.0f / fmaxf(sqrtf(norm2[i]), 1e-8f);
        float rs = 0.f;
#pragma unroll
        for (int fn = 0; fn < 4; ++fn) {
          const int j = jb + wc * 64 + fn * 16 + lx;
          float v = acc[fm][fn][r] * 2.0f * invi * invj[fn];
          if (j != i)   // i^2048 can't occur inside a diagonal block
            rs += (((i & 1024) == 0) && (j < KNOWN)) ? 1.0f : __expf(v);
        }
        rs += __shfl_xor(rs, 1);
        rs += __shfl_xor(rs, 2);
        rs += __shfl_xor(rs, 4);
        rs += __shfl_xor(rs, 8);
        if (lx == 0) atomicAdd(&sumexp[i], rs);
      }
    }
  } else {
    float cs[4] = {0.f, 0.f, 0.f, 0.f};
#pragma unroll
    for (int fm = 0; fm < 4; ++fm) {
#pragma unroll
      for (int r = 0; r < 4; ++r) {
        const int i = ib + wr * 64 + fm * 16 + (l >> 4) * 4 + r;
        const float invi = 1.0f / fmaxf(sqrtf(norm2[i]), 1e-8f);
        float rs = 0.f;
#pragma unroll
        for (int fn = 0; fn < 4; ++fn) {
          const int j = jb + wc * 64 + fn * 16 + lx;
          float v = acc[fm][fn][r] * 2.0f * invi * invj[fn];
          if (j == (i ^ 2048)) {
            pos[i] = v;          // symmetric entry, same value
            pos[j] = v;
          } else {               // j != i always holds off-diagonal
            float e = __expf(v);
            rs += (((i & 1024) == 0) && (j < KNOWN)) ? 1.0f : e;
            cs[fn] += (((j & 1024) == 0) && (i < KNOWN)) ? 1.0f : e;
          }
        }
        rs += __shfl_xor(rs, 1);
        rs += __shfl_xor(rs, 2);
        rs += __shfl_xor(rs, 4);
        rs += __shfl_xor(rs, 8);
        if (lx == 0) atomicAdd(&sumexp[i], rs);
      }
    }
#pragma unroll
    for (int fn = 0; fn < 4; ++fn) {
      cs[fn] += __shfl_xor(cs[fn], 16);
      cs[fn] += __shfl_xor(cs[fn], 32);
    }
    if (l < 16) {
#pragma unroll
      for (int fn = 0; fn < 4; ++fn)
        atomicAdd(&sumexp[jb + wc * 64 + fn * 16 + l], cs[fn]);
    }
  }
}

// ---- Kernel 3: finalize ---------------------------------------------------
__device__ float block_reduce_256(float v, volatile float* red) {
#pragma unroll
  for (int m = 32; m >= 1; m >>= 1) v += __shfl_xor(v, m);
  __syncthreads();
  if ((threadIdx.x & 63) == 0) red[threadIdx.x >> 6] = v;
  __syncthreads();
  return red[0] + red[1] + red[2] + red[3];
}

__global__ void finalize_kernel(const float* __restrict__ colsum,
                                const float* __restrict__ sumexp,
                                const float* __restrict__ pos,
                                float* __restrict__ out) {
  __shared__ float red[4];
  int t = threadIdx.x;
  float ce = 0.f, t1 = 0.f, t2 = 0.f;
  for (int i = t; i < N_TOT; i += 256) ce += logf(sumexp[i]) - pos[i];
  for (int c = t; c < C_NUM; c += 256) t1 += colsum[c];
  for (int c = t; c < C_NUM; c += 256) t2 += colsum[C_NUM + c];
  ce = block_reduce_256(ce, red);
  t1 = block_reduce_256(t1, red);
  t2 = block_reduce_256(t2, red);
  float e1 = 0.f, e2 = 0.f;
  for (int c = t; c < C_NUM; c += 256) {
    float m = colsum[c] / t1;
    e1 += m * logf(m);
  }
  for (int c = t; c < C_NUM; c += 256) {
    float m = colsum[C_NUM + c] / t2;
    e2 += m * logf(m);
  }
  e1 = block_reduce_256(e1, red);
  e2 = block_reduce_256(e2, red);
  if (t == 0) {
    float reg = logf((float)C_NUM) + e1 + logf((float)C_NUM) + e2;
    out[0] = ce / (float)N_TOT + reg;
  }
}

extern "C" void kernel_launch(void* const* d_in, const int* in_sizes, int n_in,
                              void* d_out, int out_size, void* d_ws, size_t ws_size,
                              hipStream_t stream) {
  const float* prob = (const float*)d_in[0];
  const float* prob_s = (const float*)d_in[1];
  float* out = (float*)d_out;

  char* ws = (char*)d_ws;
  uint8_t* Pn = (uint8_t*)ws;                                   // 16 MB fp8
  float* norm2 = (float*)(ws + (size_t)N_TOT * B_TOT);          // 4096 f32
  float* colsum = norm2 + N_TOT;                                // 4096 f32
  float* sumexp = colsum + N_TOT;                               // 4096 f32
  float* pos = sumexp + N_TOT;                                  // 4096 f32

  // zero the atomic accumulators (norm2, colsum, sumexp contiguous)
  hipMemsetAsync(norm2, 0, (size_t)3 * N_TOT * sizeof(float), stream);

  transpose_stats_kernel<<<dim3(64, 64), 256, 0, stream>>>(
      prob, prob_s, colsum, norm2, Pn);
  simgemm_kernel<<<528, 256, 0, stream>>>(Pn, norm2, sumexp, pos);
  finalize_kernel<<<1, 256, 0, stream>>>(colsum, sumexp, pos, out);
}